// Round 1
// baseline (553.214 us; speedup 1.0000x reference)
//
#include <hip/hip_runtime.h>
#include <math.h>

#define NUM_CLASSES 26
#define HH 512
#define WW 512
#define NB 4
#define PHH 171
#define PWW 171
#define NHH 169
#define NWW 169
#define MPTS (NHH*NWW)        // 28561
#define NCT (NB*NUM_CLASSES)  // 104
#define CLIPV 1e-6f
#define NCHUNK 13             // 13 even chunks of 13 rows (13*13 = 169 = NHH)
#define RPC 13
#define TROWS (RPC+2)         // 15 pooled rows per block
#define ITEMS (RPC*43)        // 559
#define NSLOT 189             // 45 covL + 45 covP + 81 covLP + 9 sumL + 9 sumP

// LDS: pooled tiles + one reused horizontal-pool scratch (am then lm), union'd
// with the solver's fp64 workspace (solver runs only after phase 2 barrier).
struct SolveSM {
    double cl[45], cp[45], clp[81], sL[9], sP[9];
    double All[81], C[81], Pm[81], X[81], A[81];
    double red[256];
    double logacc;
};
union SMem {
    struct {
        float tP[TROWS][176];
        float tL[TROWS][176];
        float scr[4][512];     // per-wave scratch, time-shared am -> lm
    } a;                       // 29312 B  -> 5 blocks/CU
    SolveSM b;                 // 6808 B
};

// Zero the 104 per-nc counters + 1 final counter each graph replay.
__global__ void init_kernel(int* __restrict__ cnt) {
    int t = threadIdx.x;
    if (t <= NCT) cnt[t] = 0;
}

__global__ __launch_bounds__(256, 5) void fused_kernel(
        const float* __restrict__ cls, const float* __restrict__ tgt,
        const float* __restrict__ mask, float* __restrict__ partial,
        double* __restrict__ per_nc, int* __restrict__ cnt,
        float* __restrict__ out) {
    __shared__ SMem sm;
    __shared__ int winflag, finflag;
    const int nc = blockIdx.x, ch = blockIdx.y;
    const int n = nc / NUM_CLASSES;
    const int tid = threadIdx.x;
    const int lane = tid & 63, wave = tid >> 6;
    const int rowbase = ch * RPC;

    float (&tP)[TROWS][176] = sm.a.tP;
    float (&tL)[TROWS][176] = sm.a.tL;
    float (&scr)[4][512]    = sm.a.scr;

    const float4* c4 = (const float4*)(cls  + (size_t)nc * HH * WW);
    const float4* t4 = (const float4*)(tgt  + (size_t)nc * HH * WW);
    const float4* m4 = (const float4*)(mask + (size_t)n  * HH * WW);

    // ---- Phase 1: pooled rows into tile (per-wave, scratch reused am->lm) ----
    for (int k = 0; k < 4; ++k) {
        int tr = wave + 4 * k;               // wave-uniform
        if (tr >= TROWS) break;
        int ph = rowbase + tr;               // <= 170
        float am[8], lm[8];
        #pragma unroll
        for (int j = 0; j < 8; ++j) { am[j] = -INFINITY; lm[j] = 0.f; }
        const int r0 = 3 * ph - 1;
        #pragma unroll
        for (int s = 0; s < 3; ++s) {
            int r = r0 + s;
            r = r < 0 ? 0 : r;               // ph==0: duplicate row 0 (max-idempotent)
            int rb = r * 128;
            #pragma unroll
            for (int g = 0; g < 2; ++g) {
                int i4 = rb + lane + 64 * g;
                float4 c = c4[i4];
                float4 t = t4[i4];
                float4 m = m4[i4];
                float cc[4] = {c.x, c.y, c.z, c.w};
                float tt[4] = {t.x, t.y, t.z, t.w};
                float mm[4] = {m.x, m.y, m.z, m.w};
                #pragma unroll
                for (int q = 0; q < 4; ++q) {
                    int j = 4 * g + q;
                    am[j] = fmaxf(am[j], mm[q] > 0.5f ? cc[q] : -INFINITY);
                    lm[j] = fmaxf(lm[j], tt[q] * mm[q]);
                }
            }
        }
        // am pass: scratch -> horizontal max -> sigmoid -> tP
        *(float4*)&scr[wave][4 * lane]       = make_float4(am[0], am[1], am[2], am[3]);
        *(float4*)&scr[wave][256 + 4 * lane] = make_float4(am[4], am[5], am[6], am[7]);
        #pragma unroll
        for (int j = 0; j < 3; ++j) {
            int pw = lane + 64 * j;
            if (pw < PWW) {
                int cM = 3 * pw;
                float a = fmaxf(scr[wave][cM], scr[wave][cM + 1]);
                if (cM > 0) a = fmaxf(a, scr[wave][cM - 1]);
                tP[tr][pw] = __fdividef(1.0f, 1.0f + __expf(-a)) + CLIPV;
            }
        }
        if (lane < 5) tP[tr][171 + lane] = 0.f;
        // lm pass: reuse same scratch (same-wave DS ops are ordered; no barrier)
        *(float4*)&scr[wave][4 * lane]       = make_float4(lm[0], lm[1], lm[2], lm[3]);
        *(float4*)&scr[wave][256 + 4 * lane] = make_float4(lm[4], lm[5], lm[6], lm[7]);
        #pragma unroll
        for (int j = 0; j < 3; ++j) {
            int pw = lane + 64 * j;
            if (pw < PWW) {
                int cM = 3 * pw;
                float l = fmaxf(scr[wave][cM], scr[wave][cM + 1]);
                if (cM > 0) l = fmaxf(l, scr[wave][cM - 1]);
                tL[tr][pw] = (l > 0.5f) ? 1.0f : 0.0f;
            }
        }
        if (lane < 5) tL[tr][171 + lane] = 0.f;
    }
    __syncthreads();

    // ---- Phase 2: wave = mode (0=LL+sumL, 1=PP+sumP, 2=LPa d<5, 3=LPb d>=5) ----
    float* pbase = partial + (size_t)ch * NSLOT * NCT + nc;

    if (wave < 2) {
        const float (*src)[176] = wave ? tP : tL;
        float acc[45], sa[9];
        #pragma unroll
        for (int k = 0; k < 45; ++k) acc[k] = 0.f;
        #pragma unroll
        for (int k = 0; k < 9; ++k) sa[k] = 0.f;

        for (int it = lane; it < ITEMS; it += 64) {
            int tr = it / 43;
            int j0 = (it - tr * 43) * 4;
            const float* rp = &src[tr][j0];
            float4 x0 = *(const float4*)(rp);
            float4 x1 = *(const float4*)(rp + 4);
            float4 y0 = *(const float4*)(rp + 176);
            float4 y1 = *(const float4*)(rp + 180);
            float4 z0 = *(const float4*)(rp + 352);
            float4 z1 = *(const float4*)(rp + 356);
            float r0[8] = {x0.x, x0.y, x0.z, x0.w, x1.x, x1.y, x1.z, x1.w};
            float r1[8] = {y0.x, y0.y, y0.z, y0.w, y1.x, y1.y, y1.z, y1.w};
            float r2[8] = {z0.x, z0.y, z0.z, z0.w, z1.x, z1.y, z1.z, z1.w};
            #pragma unroll
            for (int q = 0; q < 4; ++q) {
                float sel = (j0 + q < NWW) ? 1.f : 0.f;
                float v[9], vs[9];
                v[0] = r0[q]; v[1] = r0[q + 1]; v[2] = r0[q + 2];
                v[3] = r1[q]; v[4] = r1[q + 1]; v[5] = r1[q + 2];
                v[6] = r2[q]; v[7] = r2[q + 1]; v[8] = r2[q + 2];
                #pragma unroll
                for (int d = 0; d < 9; ++d) { vs[d] = v[d] * sel; sa[d] += vs[d]; }
                int k = 0;
                #pragma unroll
                for (int d = 0; d < 9; ++d)
                    #pragma unroll
                    for (int e = d; e < 9; ++e)
                        acc[k++] += vs[d] * v[e];
            }
        }
        #pragma unroll
        for (int k = 0; k < 45; ++k) {
            float x = acc[k];
            #pragma unroll
            for (int off = 32; off > 0; off >>= 1) x += __shfl_down(x, off);
            if (lane == 0) pbase[(size_t)((wave == 0 ? 0 : 45) + k) * NCT] = x;
        }
        #pragma unroll
        for (int k = 0; k < 9; ++k) {
            float x = sa[k];
            #pragma unroll
            for (int off = 32; off > 0; off >>= 1) x += __shfl_down(x, off);
            if (lane == 0) pbase[(size_t)((wave == 0 ? 171 : 180) + k) * NCT] = x;
        }
    } else {
        const int nd  = (wave == 2) ? 5 : 4;
        const int dof = (wave == 2) ? 0 : 5;
        float acc[45];
        #pragma unroll
        for (int k = 0; k < 45; ++k) acc[k] = 0.f;

        for (int it = lane; it < ITEMS; it += 64) {
            int tr = it / 43;
            int j0 = (it - tr * 43) * 4;
            const float* pp = &tP[tr][j0];
            float4 px0 = *(const float4*)(pp);
            float4 px1 = *(const float4*)(pp + 4);
            float4 py0 = *(const float4*)(pp + 176);
            float4 py1 = *(const float4*)(pp + 180);
            float4 pz0 = *(const float4*)(pp + 352);
            float4 pz1 = *(const float4*)(pp + 356);
            float pr0[8] = {px0.x, px0.y, px0.z, px0.w, px1.x, px1.y, px1.z, px1.w};
            float pr1[8] = {py0.x, py0.y, py0.z, py0.w, py1.x, py1.y, py1.z, py1.w};
            float pr2[8] = {pz0.x, pz0.y, pz0.z, pz0.w, pz1.x, pz1.y, pz1.z, pz1.w};
            const float* la  = &tL[tr + (wave == 2 ? 0 : 1)][j0];
            const float* lb2 = &tL[tr + (wave == 2 ? 1 : 2)][j0];
            float4 la0 = *(const float4*)(la);
            float4 la1 = *(const float4*)(la + 4);
            float4 lb0 = *(const float4*)(lb2);
            float4 lb1 = *(const float4*)(lb2 + 4);
            float lrA[8] = {la0.x, la0.y, la0.z, la0.w, la1.x, la1.y, la1.z, la1.w};
            float lrB[8] = {lb0.x, lb0.y, lb0.z, lb0.w, lb1.x, lb1.y, lb1.z, lb1.w};
            #pragma unroll
            for (int q = 0; q < 4; ++q) {
                float sel = (j0 + q < NWW) ? 1.f : 0.f;
                float vp[9];
                vp[0] = pr0[q]; vp[1] = pr0[q + 1]; vp[2] = pr0[q + 2];
                vp[3] = pr1[q]; vp[4] = pr1[q + 1]; vp[5] = pr1[q + 2];
                vp[6] = pr2[q]; vp[7] = pr2[q + 1]; vp[8] = pr2[q + 2];
                float vl[5];
                if (wave == 2) {
                    vl[0] = lrA[q] * sel; vl[1] = lrA[q + 1] * sel; vl[2] = lrA[q + 2] * sel;
                    vl[3] = lrB[q] * sel; vl[4] = lrB[q + 1] * sel;
                } else {
                    vl[0] = lrA[q + 2] * sel;
                    vl[1] = lrB[q] * sel; vl[2] = lrB[q + 1] * sel; vl[3] = lrB[q + 2] * sel;
                }
                #pragma unroll
                for (int d = 0; d < 5; ++d) {
                    if (d < nd) {
                        #pragma unroll
                        for (int e = 0; e < 9; ++e)
                            acc[d * 9 + e] += vl[d] * vp[e];
                    }
                }
            }
        }
        const int nred = nd * 9;
        #pragma unroll
        for (int k = 0; k < 45; ++k) {
            if (k < nred) {
                float x = acc[k];
                #pragma unroll
                for (int off = 32; off > 0; off >>= 1) x += __shfl_down(x, off);
                if (lane == 0) pbase[(size_t)(90 + dof * 9 + k) * NCT] = x;
            }
        }
    }

    // ---- last-block election for this nc (release: fence storers, then atomic) ----
    if (lane == 0) __threadfence();      // each wave's storer flushes its stores
    __syncthreads();
    if (tid == 0) {
        int old = atomicAdd(&cnt[nc], 1);
        winflag = (old == NCHUNK - 1);
    }
    __syncthreads();
    if (!winflag) return;
    __threadfence();                     // acquire: invalidate stale cache lines

    // ---- solve: per-(n,c) 9x9 algebra, 256 threads, LDS union'd over tiles ----
    SolveSM& S = sm.b;
    if (tid < NSLOT) {
        double acc = 0.0;
        #pragma unroll
        for (int c2 = 0; c2 < NCHUNK; ++c2)
            acc += (double)partial[((size_t)c2 * NSLOT + tid) * NCT + nc];
        if (tid < 45)       S.cl[tid] = acc;
        else if (tid < 90)  S.cp[tid - 45] = acc;
        else if (tid < 171) S.clp[tid - 90] = acc;
        else if (tid < 180) S.sL[tid - 171] = acc;
        else                S.sP[tid - 180] = acc;
    }
    if (tid == 0) S.logacc = 0.0;
    __syncthreads();

    const double M = (double)MPTS;
    if (tid < 81) {
        int d = tid / 9, e = tid % 9;
        int lo = d < e ? d : e, hi = d < e ? e : d;
        int kk = 9 * lo - lo * (lo - 1) / 2 + (hi - lo);
        S.All[tid] = S.cl[kk] - S.sL[d] * S.sL[e] / M;
        S.C[tid]   = S.cp[kk] - S.sP[d] * S.sP[e] / M + (d == e ? 1e-3 : 0.0);
        S.Pm[tid]  = S.clp[tid] - S.sL[d] * S.sP[e] / M;
    }
    __syncthreads();

    for (int kk = 0; kk < 9; ++kk) {
        if (tid == 0) S.C[kk * 9 + kk] = sqrt(fmax(S.C[kk * 9 + kk], 1e-30));
        __syncthreads();
        if (tid > kk && tid < 9) S.C[tid * 9 + kk] /= S.C[kk * 9 + kk];
        __syncthreads();
        if (tid < 81) {
            int i = tid / 9, j = tid % 9;
            if (j > kk && i >= j) S.C[i * 9 + j] -= S.C[i * 9 + kk] * S.C[j * 9 + kk];
        }
        __syncthreads();
    }

    for (int e = 0; e < 9; ++e) {
        if (tid < 9) {
            int d = tid;
            double sum = S.Pm[d * 9 + e];
            for (int kk = 0; kk < e; ++kk) sum -= S.C[e * 9 + kk] * S.X[kk * 9 + d];
            S.X[e * 9 + d] = sum / S.C[e * 9 + e];
        }
        __syncthreads();
    }

    if (tid < 81) {
        int d = tid / 9, g = tid % 9;
        double w = 0.0;
        #pragma unroll
        for (int e = 0; e < 9; ++e) w += S.X[e * 9 + d] * S.X[e * 9 + g];
        S.A[tid] = S.All[tid] - w + (d == g ? 1e-3 : 0.0);
    }
    __syncthreads();

    for (int kk = 0; kk < 9; ++kk) {
        if (tid == 0) {
            double piv = sqrt(fmax(S.A[kk * 9 + kk], 0.0));
            S.A[kk * 9 + kk] = piv;
            S.logacc += log(piv + 1e-8);
        }
        __syncthreads();
        if (tid > kk && tid < 9) S.A[tid * 9 + kk] /= S.A[kk * 9 + kk];
        __syncthreads();
        if (tid < 81) {
            int i = tid / 9, j = tid % 9;
            if (j > kk && i >= j) S.A[i * 9 + j] -= S.A[i * 9 + kk] * S.A[j * 9 + kk];
        }
        __syncthreads();
    }
    if (tid == 0) per_nc[nc] = S.logacc;

    // ---- last-solver election for final 104 -> 1 reduction ----
    if (tid == 0) {
        __threadfence();                 // flush per_nc[nc] (written by tid 0)
        int o = atomicAdd(&cnt[NCT], 1);
        finflag = (o == NCT - 1);
    }
    __syncthreads();
    if (!finflag) return;
    __threadfence();                     // acquire before reading all per_nc

    S.red[tid] = (tid < NCT) ? per_nc[tid] : 0.0;
    __syncthreads();
    for (int s2 = 128; s2 > 0; s2 >>= 1) {
        if (tid < s2) S.red[tid] += S.red[tid + s2];
        __syncthreads();
    }
    if (tid == 0) out[0] = (float)(S.red[0] / 36.0);
}

extern "C" void kernel_launch(void* const* d_in, const int* in_sizes, int n_in,
                              void* d_out, int out_size, void* d_ws, size_t ws_size,
                              hipStream_t stream) {
    const float* cls  = (const float*)d_in[0];
    const float* tgt  = (const float*)d_in[1];
    const float* mask = (const float*)d_in[2];

    // ws layout: per_nc (104 doubles) | cnt (105 ints, padded to 112) | partial
    double* per_nc  = (double*)d_ws;
    int*    cnt     = (int*)(per_nc + NCT);
    float*  partial = (float*)((char*)d_ws + NCT * 8 + 112 * 4);  // 1280 B offset

    init_kernel<<<1, 128, 0, stream>>>(cnt);
    dim3 gfused(NCT, NCHUNK);
    fused_kernel<<<gfused, 256, 0, stream>>>(cls, tgt, mask, partial, per_nc, cnt,
                                             (float*)d_out);
}

// Round 2
// 454.055 us; speedup vs baseline: 1.2184x; 1.2184x over previous
//
#include <hip/hip_runtime.h>
#include <math.h>

#define NUM_CLASSES 26
#define HH 512
#define WW 512
#define NB 4
#define PHH 171
#define PWW 171
#define NHH 169
#define NWW 169
#define MPTS (NHH*NWW)        // 28561
#define NCT (NB*NUM_CLASSES)  // 104
#define CLIPV 1e-6f
#define NCHUNK 13             // 13 even chunks of 13 rows (13*13 = 169 = NHH)
#define RPC 13
#define TROWS (RPC+2)         // 15 pooled rows per block
#define ITEMS (RPC*43)        // 559
#define NSLOT 189             // 45 covL + 45 covP + 81 covLP + 9 sumL + 9 sumP

// LDS: pooled tiles + one reused horizontal-pool scratch (am then lm), union'd
// with the solver's fp64 workspace (solver runs only after phase 2 barrier).
struct SolveSM {
    double cl[45], cp[45], clp[81], sL[9], sP[9];
    double All[81], C[81], Pm[81], X[81], A[81];
    double red[256];
    double logacc;
};
union SMem {
    struct {
        float tP[TROWS][176];
        float tL[TROWS][176];
        float scr[4][512];     // per-wave scratch, time-shared am -> lm
    } a;                       // 29312 B  -> 5 blocks/CU by LDS
    SolveSM b;                 // 6808 B
};

// Zero the 104 per-nc counters + 1 final counter each graph replay.
__global__ void init_kernel(int* __restrict__ cnt) {
    int t = threadIdx.x;
    if (t <= NCT) cnt[t] = 0;
}

// launch_bounds(256,3): minimum-occupancy hint only. Round-1's (256,5) capped
// VGPR at 48 -> acc[45] spilled -> 304 MB scratch writes, 3.4x slowdown.
// With ~84-110 VGPRs the HW still fits ~5 blocks/CU (LDS 29.3 KB is the limit).
__global__ __launch_bounds__(256, 3) void fused_kernel(
        const float* __restrict__ cls, const float* __restrict__ tgt,
        const float* __restrict__ mask, float* __restrict__ partial,
        double* __restrict__ per_nc, int* __restrict__ cnt,
        float* __restrict__ out) {
    __shared__ SMem sm;
    __shared__ int winflag, finflag;
    const int nc = blockIdx.x, ch = blockIdx.y;
    const int n = nc / NUM_CLASSES;
    const int tid = threadIdx.x;
    const int lane = tid & 63, wave = tid >> 6;
    const int rowbase = ch * RPC;

    float (&tP)[TROWS][176] = sm.a.tP;
    float (&tL)[TROWS][176] = sm.a.tL;
    float (&scr)[4][512]    = sm.a.scr;

    const float4* c4 = (const float4*)(cls  + (size_t)nc * HH * WW);
    const float4* t4 = (const float4*)(tgt  + (size_t)nc * HH * WW);
    const float4* m4 = (const float4*)(mask + (size_t)n  * HH * WW);

    // ---- Phase 1: pooled rows into tile (per-wave, scratch reused am->lm) ----
    for (int k = 0; k < 4; ++k) {
        int tr = wave + 4 * k;               // wave-uniform
        if (tr >= TROWS) break;
        int ph = rowbase + tr;               // <= 170
        float am[8], lm[8];
        #pragma unroll
        for (int j = 0; j < 8; ++j) { am[j] = -INFINITY; lm[j] = 0.f; }
        const int r0 = 3 * ph - 1;
        #pragma unroll
        for (int s = 0; s < 3; ++s) {
            int r = r0 + s;
            r = r < 0 ? 0 : r;               // ph==0: duplicate row 0 (max-idempotent)
            int rb = r * 128;
            #pragma unroll
            for (int g = 0; g < 2; ++g) {
                int i4 = rb + lane + 64 * g;
                float4 c = c4[i4];
                float4 t = t4[i4];
                float4 m = m4[i4];
                float cc[4] = {c.x, c.y, c.z, c.w};
                float tt[4] = {t.x, t.y, t.z, t.w};
                float mm[4] = {m.x, m.y, m.z, m.w};
                #pragma unroll
                for (int q = 0; q < 4; ++q) {
                    int j = 4 * g + q;
                    am[j] = fmaxf(am[j], mm[q] > 0.5f ? cc[q] : -INFINITY);
                    lm[j] = fmaxf(lm[j], tt[q] * mm[q]);
                }
            }
        }
        // am pass: scratch -> horizontal max -> sigmoid -> tP
        *(float4*)&scr[wave][4 * lane]       = make_float4(am[0], am[1], am[2], am[3]);
        *(float4*)&scr[wave][256 + 4 * lane] = make_float4(am[4], am[5], am[6], am[7]);
        #pragma unroll
        for (int j = 0; j < 3; ++j) {
            int pw = lane + 64 * j;
            if (pw < PWW) {
                int cM = 3 * pw;
                float a = fmaxf(scr[wave][cM], scr[wave][cM + 1]);
                if (cM > 0) a = fmaxf(a, scr[wave][cM - 1]);
                tP[tr][pw] = __fdividef(1.0f, 1.0f + __expf(-a)) + CLIPV;
            }
        }
        if (lane < 5) tP[tr][171 + lane] = 0.f;
        // lm pass: reuse same scratch (same-wave DS ops are ordered; no barrier)
        *(float4*)&scr[wave][4 * lane]       = make_float4(lm[0], lm[1], lm[2], lm[3]);
        *(float4*)&scr[wave][256 + 4 * lane] = make_float4(lm[4], lm[5], lm[6], lm[7]);
        #pragma unroll
        for (int j = 0; j < 3; ++j) {
            int pw = lane + 64 * j;
            if (pw < PWW) {
                int cM = 3 * pw;
                float l = fmaxf(scr[wave][cM], scr[wave][cM + 1]);
                if (cM > 0) l = fmaxf(l, scr[wave][cM - 1]);
                tL[tr][pw] = (l > 0.5f) ? 1.0f : 0.0f;
            }
        }
        if (lane < 5) tL[tr][171 + lane] = 0.f;
    }
    __syncthreads();

    // ---- Phase 2: wave = mode (0=LL+sumL, 1=PP+sumP, 2=LPa d<5, 3=LPb d>=5) ----
    float* pbase = partial + (size_t)ch * NSLOT * NCT + nc;

    if (wave < 2) {
        const float (*src)[176] = wave ? tP : tL;
        float acc[45], sa[9];
        #pragma unroll
        for (int k = 0; k < 45; ++k) acc[k] = 0.f;
        #pragma unroll
        for (int k = 0; k < 9; ++k) sa[k] = 0.f;

        for (int it = lane; it < ITEMS; it += 64) {
            int tr = it / 43;
            int j0 = (it - tr * 43) * 4;
            const float* rp = &src[tr][j0];
            float4 x0 = *(const float4*)(rp);
            float4 x1 = *(const float4*)(rp + 4);
            float4 y0 = *(const float4*)(rp + 176);
            float4 y1 = *(const float4*)(rp + 180);
            float4 z0 = *(const float4*)(rp + 352);
            float4 z1 = *(const float4*)(rp + 356);
            float r0[8] = {x0.x, x0.y, x0.z, x0.w, x1.x, x1.y, x1.z, x1.w};
            float r1[8] = {y0.x, y0.y, y0.z, y0.w, y1.x, y1.y, y1.z, y1.w};
            float r2[8] = {z0.x, z0.y, z0.z, z0.w, z1.x, z1.y, z1.z, z1.w};
            #pragma unroll
            for (int q = 0; q < 4; ++q) {
                float sel = (j0 + q < NWW) ? 1.f : 0.f;
                float v[9], vs[9];
                v[0] = r0[q]; v[1] = r0[q + 1]; v[2] = r0[q + 2];
                v[3] = r1[q]; v[4] = r1[q + 1]; v[5] = r1[q + 2];
                v[6] = r2[q]; v[7] = r2[q + 1]; v[8] = r2[q + 2];
                #pragma unroll
                for (int d = 0; d < 9; ++d) { vs[d] = v[d] * sel; sa[d] += vs[d]; }
                int k = 0;
                #pragma unroll
                for (int d = 0; d < 9; ++d)
                    #pragma unroll
                    for (int e = d; e < 9; ++e)
                        acc[k++] += vs[d] * v[e];
            }
        }
        #pragma unroll
        for (int k = 0; k < 45; ++k) {
            float x = acc[k];
            #pragma unroll
            for (int off = 32; off > 0; off >>= 1) x += __shfl_down(x, off);
            if (lane == 0) pbase[(size_t)((wave == 0 ? 0 : 45) + k) * NCT] = x;
        }
        #pragma unroll
        for (int k = 0; k < 9; ++k) {
            float x = sa[k];
            #pragma unroll
            for (int off = 32; off > 0; off >>= 1) x += __shfl_down(x, off);
            if (lane == 0) pbase[(size_t)((wave == 0 ? 171 : 180) + k) * NCT] = x;
        }
    } else {
        const int nd  = (wave == 2) ? 5 : 4;
        const int dof = (wave == 2) ? 0 : 5;
        float acc[45];
        #pragma unroll
        for (int k = 0; k < 45; ++k) acc[k] = 0.f;

        for (int it = lane; it < ITEMS; it += 64) {
            int tr = it / 43;
            int j0 = (it - tr * 43) * 4;
            const float* pp = &tP[tr][j0];
            float4 px0 = *(const float4*)(pp);
            float4 px1 = *(const float4*)(pp + 4);
            float4 py0 = *(const float4*)(pp + 176);
            float4 py1 = *(const float4*)(pp + 180);
            float4 pz0 = *(const float4*)(pp + 352);
            float4 pz1 = *(const float4*)(pp + 356);
            float pr0[8] = {px0.x, px0.y, px0.z, px0.w, px1.x, px1.y, px1.z, px1.w};
            float pr1[8] = {py0.x, py0.y, py0.z, py0.w, py1.x, py1.y, py1.z, py1.w};
            float pr2[8] = {pz0.x, pz0.y, pz0.z, pz0.w, pz1.x, pz1.y, pz1.z, pz1.w};
            const float* la  = &tL[tr + (wave == 2 ? 0 : 1)][j0];
            const float* lb2 = &tL[tr + (wave == 2 ? 1 : 2)][j0];
            float4 la0 = *(const float4*)(la);
            float4 la1 = *(const float4*)(la + 4);
            float4 lb0 = *(const float4*)(lb2);
            float4 lb1 = *(const float4*)(lb2 + 4);
            float lrA[8] = {la0.x, la0.y, la0.z, la0.w, la1.x, la1.y, la1.z, la1.w};
            float lrB[8] = {lb0.x, lb0.y, lb0.z, lb0.w, lb1.x, lb1.y, lb1.z, lb1.w};
            #pragma unroll
            for (int q = 0; q < 4; ++q) {
                float sel = (j0 + q < NWW) ? 1.f : 0.f;
                float vp[9];
                vp[0] = pr0[q]; vp[1] = pr0[q + 1]; vp[2] = pr0[q + 2];
                vp[3] = pr1[q]; vp[4] = pr1[q + 1]; vp[5] = pr1[q + 2];
                vp[6] = pr2[q]; vp[7] = pr2[q + 1]; vp[8] = pr2[q + 2];
                float vl[5];
                if (wave == 2) {
                    vl[0] = lrA[q] * sel; vl[1] = lrA[q + 1] * sel; vl[2] = lrA[q + 2] * sel;
                    vl[3] = lrB[q] * sel; vl[4] = lrB[q + 1] * sel;
                } else {
                    vl[0] = lrA[q + 2] * sel;
                    vl[1] = lrB[q] * sel; vl[2] = lrB[q + 1] * sel; vl[3] = lrB[q + 2] * sel;
                }
                #pragma unroll
                for (int d = 0; d < 5; ++d) {
                    if (d < nd) {
                        #pragma unroll
                        for (int e = 0; e < 9; ++e)
                            acc[d * 9 + e] += vl[d] * vp[e];
                    }
                }
            }
        }
        const int nred = nd * 9;
        #pragma unroll
        for (int k = 0; k < 45; ++k) {
            if (k < nred) {
                float x = acc[k];
                #pragma unroll
                for (int off = 32; off > 0; off >>= 1) x += __shfl_down(x, off);
                if (lane == 0) pbase[(size_t)(90 + dof * 9 + k) * NCT] = x;
            }
        }
    }

    // ---- last-block election for this nc (release: fence storers, then atomic) ----
    if (lane == 0) __threadfence();      // each wave's storer flushes its stores
    __syncthreads();
    if (tid == 0) {
        int old = atomicAdd(&cnt[nc], 1);
        winflag = (old == NCHUNK - 1);
    }
    __syncthreads();
    if (!winflag) return;
    __threadfence();                     // acquire: invalidate stale cache lines

    // ---- solve: per-(n,c) 9x9 algebra, 256 threads, LDS union'd over tiles ----
    SolveSM& S = sm.b;
    if (tid < NSLOT) {
        double acc = 0.0;
        #pragma unroll
        for (int c2 = 0; c2 < NCHUNK; ++c2)
            acc += (double)partial[((size_t)c2 * NSLOT + tid) * NCT + nc];
        if (tid < 45)       S.cl[tid] = acc;
        else if (tid < 90)  S.cp[tid - 45] = acc;
        else if (tid < 171) S.clp[tid - 90] = acc;
        else if (tid < 180) S.sL[tid - 171] = acc;
        else                S.sP[tid - 180] = acc;
    }
    if (tid == 0) S.logacc = 0.0;
    __syncthreads();

    const double M = (double)MPTS;
    if (tid < 81) {
        int d = tid / 9, e = tid % 9;
        int lo = d < e ? d : e, hi = d < e ? e : d;
        int kk = 9 * lo - lo * (lo - 1) / 2 + (hi - lo);
        S.All[tid] = S.cl[kk] - S.sL[d] * S.sL[e] / M;
        S.C[tid]   = S.cp[kk] - S.sP[d] * S.sP[e] / M + (d == e ? 1e-3 : 0.0);
        S.Pm[tid]  = S.clp[tid] - S.sL[d] * S.sP[e] / M;
    }
    __syncthreads();

    for (int kk = 0; kk < 9; ++kk) {
        if (tid == 0) S.C[kk * 9 + kk] = sqrt(fmax(S.C[kk * 9 + kk], 1e-30));
        __syncthreads();
        if (tid > kk && tid < 9) S.C[tid * 9 + kk] /= S.C[kk * 9 + kk];
        __syncthreads();
        if (tid < 81) {
            int i = tid / 9, j = tid % 9;
            if (j > kk && i >= j) S.C[i * 9 + j] -= S.C[i * 9 + kk] * S.C[j * 9 + kk];
        }
        __syncthreads();
    }

    for (int e = 0; e < 9; ++e) {
        if (tid < 9) {
            int d = tid;
            double sum = S.Pm[d * 9 + e];
            for (int kk = 0; kk < e; ++kk) sum -= S.C[e * 9 + kk] * S.X[kk * 9 + d];
            S.X[e * 9 + d] = sum / S.C[e * 9 + e];
        }
        __syncthreads();
    }

    if (tid < 81) {
        int d = tid / 9, g = tid % 9;
        double w = 0.0;
        #pragma unroll
        for (int e = 0; e < 9; ++e) w += S.X[e * 9 + d] * S.X[e * 9 + g];
        S.A[tid] = S.All[tid] - w + (d == g ? 1e-3 : 0.0);
    }
    __syncthreads();

    for (int kk = 0; kk < 9; ++kk) {
        if (tid == 0) {
            double piv = sqrt(fmax(S.A[kk * 9 + kk], 0.0));
            S.A[kk * 9 + kk] = piv;
            S.logacc += log(piv + 1e-8);
        }
        __syncthreads();
        if (tid > kk && tid < 9) S.A[tid * 9 + kk] /= S.A[kk * 9 + kk];
        __syncthreads();
        if (tid < 81) {
            int i = tid / 9, j = tid % 9;
            if (j > kk && i >= j) S.A[i * 9 + j] -= S.A[i * 9 + kk] * S.A[j * 9 + kk];
        }
        __syncthreads();
    }
    if (tid == 0) per_nc[nc] = S.logacc;

    // ---- last-solver election for final 104 -> 1 reduction ----
    if (tid == 0) {
        __threadfence();                 // flush per_nc[nc] (written by tid 0)
        int o = atomicAdd(&cnt[NCT], 1);
        finflag = (o == NCT - 1);
    }
    __syncthreads();
    if (!finflag) return;
    __threadfence();                     // acquire before reading all per_nc

    S.red[tid] = (tid < NCT) ? per_nc[tid] : 0.0;
    __syncthreads();
    for (int s2 = 128; s2 > 0; s2 >>= 1) {
        if (tid < s2) S.red[tid] += S.red[tid + s2];
        __syncthreads();
    }
    if (tid == 0) out[0] = (float)(S.red[0] / 36.0);
}

extern "C" void kernel_launch(void* const* d_in, const int* in_sizes, int n_in,
                              void* d_out, int out_size, void* d_ws, size_t ws_size,
                              hipStream_t stream) {
    const float* cls  = (const float*)d_in[0];
    const float* tgt  = (const float*)d_in[1];
    const float* mask = (const float*)d_in[2];

    // ws layout: per_nc (104 doubles) | cnt (105 ints, padded to 112) | partial
    double* per_nc  = (double*)d_ws;
    int*    cnt     = (int*)(per_nc + NCT);
    float*  partial = (float*)((char*)d_ws + NCT * 8 + 112 * 4);  // 1280 B offset

    init_kernel<<<1, 128, 0, stream>>>(cnt);
    dim3 gfused(NCT, NCHUNK);
    fused_kernel<<<gfused, 256, 0, stream>>>(cls, tgt, mask, partial, per_nc, cnt,
                                             (float*)d_out);
}

// Round 8
// 307.871 us; speedup vs baseline: 1.7969x; 1.4748x over previous
//
#include <hip/hip_runtime.h>
#include <math.h>

#define NUM_CLASSES 26
#define HH 512
#define WW 512
#define NB 4
#define PHH 171
#define PWW 171
#define NHH 169
#define NWW 169
#define MPTS (NHH*NWW)        // 28561
#define NCT (NB*NUM_CLASSES)  // 104
#define CLIPV 1e-6f
#define NCHUNK 8
#define RPC 22                // rows per chunk (last: 15)
#define NSLOT 189             // 45 covL + 45 covP + 81 covLP + 9 sumL + 9 sumP
// ws footprint: 128 doubles (1024 B) + 8*189*104 floats (628992 B) = 630 KB.
// This is the ONLY layout that has passed ALL harness checks (round 0).
// Rounds 1-7 used a 1.02 MB layout (NCHUNK=13); evidence (R6 first-launch-pass/
// later-launch-drift, R7 zero_ws making the FIRST launch worse) points to that
// footprint exceeding ws_size on some containers -> OOB writes. Stay <= 630 KB.

// ---------- Kernel 1: fused maxpool + covariance partials ----------
// Phase 1 is REFERENCE-FAITHFUL (kept from round 6, value-identical on binary
// inputs, strictly safer on arbitrary floats):
//   probs  = sigmoid(cls)*mask + 1e-6  per PIXEL, then maxpool
//   labels = tgt*mask                  per PIXEL, then maxpool (no threshold)
__global__ __launch_bounds__(256, 3) void fused_kernel(const float* __restrict__ cls,
        const float* __restrict__ tgt, const float* __restrict__ mask,
        float* __restrict__ partial) {
    const int nc = blockIdx.x, ch = blockIdx.y;
    const int n = nc / NUM_CLASSES;
    const int lane = threadIdx.x & 63, wave = threadIdx.x >> 6;
    const int rowbase = ch * RPC;
    const int rc = (rowbase + RPC <= NHH) ? RPC : (NHH - rowbase);
    const int trows = rc + 2;     // pooled rows needed (<=24); ph max = 170

    __shared__ float tP[24][176];
    __shared__ float tL[24][176];
    __shared__ float pmS[4][512];
    __shared__ float lmS[4][512];

    const float4* c4 = (const float4*)(cls  + (size_t)nc * HH * WW);
    const float4* t4 = (const float4*)(tgt  + (size_t)nc * HH * WW);
    const float4* m4 = (const float4*)(mask + (size_t)n  * HH * WW);

    // ---- Phase 1: pooled rows into tile ----
    for (int k = 0; k < 6; ++k) {
        int tr = wave + 4 * k;               // wave-uniform
        if (tr >= trows) break;
        int ph = rowbase + tr;
        float pm[8], lm[8];
        #pragma unroll
        for (int j = 0; j < 8; ++j) { pm[j] = -INFINITY; lm[j] = -INFINITY; }
        const int r0 = 3 * ph - 1;
        #pragma unroll
        for (int s = 0; s < 3; ++s) {
            int r = r0 + s;
            r = r < 0 ? 0 : r;               // ph==0: duplicate row 0 (max-idempotent)
            int rb = r * 128;
            #pragma unroll
            for (int g = 0; g < 2; ++g) {
                int i4 = rb + lane + 64 * g;
                float4 c = c4[i4];
                float4 t = t4[i4];
                float4 m = m4[i4];
                float cc[4] = {c.x, c.y, c.z, c.w};
                float tt[4] = {t.x, t.y, t.z, t.w};
                float mm[4] = {m.x, m.y, m.z, m.w};
                #pragma unroll
                for (int q = 0; q < 4; ++q) {
                    int j = 4 * g + q;
                    // per-pixel prob exactly as reference, then pool
                    float p = __fdividef(1.0f, 1.0f + __expf(-cc[q])) * mm[q] + CLIPV;
                    pm[j] = fmaxf(pm[j], p);
                    lm[j] = fmaxf(lm[j], tt[q] * mm[q]);
                }
            }
        }
        // cols 4*lane..4*lane+3 (g=0) and 256+4*lane.. (g=1)
        *(float4*)&pmS[wave][4 * lane]       = make_float4(pm[0], pm[1], pm[2], pm[3]);
        *(float4*)&pmS[wave][256 + 4 * lane] = make_float4(pm[4], pm[5], pm[6], pm[7]);
        *(float4*)&lmS[wave][4 * lane]       = make_float4(lm[0], lm[1], lm[2], lm[3]);
        *(float4*)&lmS[wave][256 + 4 * lane] = make_float4(lm[4], lm[5], lm[6], lm[7]);
        // same wave reads its own scratch: compiler inserts lgkmcnt wait, no barrier
        #pragma unroll
        for (int j = 0; j < 3; ++j) {
            int pw = lane + 64 * j;
            if (pw < PWW) {
                int cM = 3 * pw;             // window cols cM-1..cM+1 (cM+1<=511)
                float a = fmaxf(pmS[wave][cM], pmS[wave][cM + 1]);
                float l = fmaxf(lmS[wave][cM], lmS[wave][cM + 1]);
                if (cM > 0) {
                    a = fmaxf(a, pmS[wave][cM - 1]);
                    l = fmaxf(l, lmS[wave][cM - 1]);
                }
                tP[tr][pw] = a;              // pooled prob (sigmoid already applied)
                tL[tr][pw] = l;              // pooled label (no threshold)
            }
        }
        if (lane < 5) {                      // zero pad cols 171..175
            tP[tr][171 + lane] = 0.f;
            tL[tr][171 + lane] = 0.f;
        }
    }
    __syncthreads();

    // ---- Phase 2: wave = mode ----
    const int items = rc * 43;
    float* pbase = partial + (size_t)ch * NSLOT * NCT + nc;

    if (wave < 2) {
        const float (*src)[176] = wave ? tP : tL;
        float acc[45], sm[9];
        #pragma unroll
        for (int k = 0; k < 45; ++k) acc[k] = 0.f;
        #pragma unroll
        for (int k = 0; k < 9; ++k) sm[k] = 0.f;

        for (int it = lane; it < items; it += 64) {
            int tr = it / 43;
            int j0 = (it - tr * 43) * 4;
            const float* rp = &src[tr][j0];
            float4 x0 = *(const float4*)(rp);
            float4 x1 = *(const float4*)(rp + 4);
            float4 y0 = *(const float4*)(rp + 176);
            float4 y1 = *(const float4*)(rp + 180);
            float4 z0 = *(const float4*)(rp + 352);
            float4 z1 = *(const float4*)(rp + 356);
            float r0[8] = {x0.x, x0.y, x0.z, x0.w, x1.x, x1.y, x1.z, x1.w};
            float r1[8] = {y0.x, y0.y, y0.z, y0.w, y1.x, y1.y, y1.z, y1.w};
            float r2[8] = {z0.x, z0.y, z0.z, z0.w, z1.x, z1.y, z1.z, z1.w};
            #pragma unroll
            for (int q = 0; q < 4; ++q) {
                float sel = (j0 + q < NWW) ? 1.f : 0.f;
                float v[9], vs[9];
                v[0] = r0[q]; v[1] = r0[q + 1]; v[2] = r0[q + 2];
                v[3] = r1[q]; v[4] = r1[q + 1]; v[5] = r1[q + 2];
                v[6] = r2[q]; v[7] = r2[q + 1]; v[8] = r2[q + 2];
                #pragma unroll
                for (int d = 0; d < 9; ++d) { vs[d] = v[d] * sel; sm[d] += vs[d]; }
                int k = 0;
                #pragma unroll
                for (int d = 0; d < 9; ++d)
                    #pragma unroll
                    for (int e = d; e < 9; ++e)
                        acc[k++] += vs[d] * v[e];
            }
        }
        #pragma unroll
        for (int k = 0; k < 45; ++k) {
            float x = acc[k];
            #pragma unroll
            for (int off = 32; off > 0; off >>= 1) x += __shfl_down(x, off);
            if (lane == 0) pbase[(size_t)((wave == 0 ? 0 : 45) + k) * NCT] = x;
        }
        #pragma unroll
        for (int k = 0; k < 9; ++k) {
            float x = sm[k];
            #pragma unroll
            for (int off = 32; off > 0; off >>= 1) x += __shfl_down(x, off);
            if (lane == 0) pbase[(size_t)((wave == 0 ? 171 : 180) + k) * NCT] = x;
        }
    } else {
        // LPa (wave 2): d=0..4 ; LPb (wave 3): d=5..8
        const int nd  = (wave == 2) ? 5 : 4;
        const int dof = (wave == 2) ? 0 : 5;
        float acc[45];
        #pragma unroll
        for (int k = 0; k < 45; ++k) acc[k] = 0.f;

        for (int it = lane; it < items; it += 64) {
            int tr = it / 43;
            int j0 = (it - tr * 43) * 4;
            const float* pp = &tP[tr][j0];
            float4 px0 = *(const float4*)(pp);
            float4 px1 = *(const float4*)(pp + 4);
            float4 py0 = *(const float4*)(pp + 176);
            float4 py1 = *(const float4*)(pp + 180);
            float4 pz0 = *(const float4*)(pp + 352);
            float4 pz1 = *(const float4*)(pp + 356);
            float pr0[8] = {px0.x, px0.y, px0.z, px0.w, px1.x, px1.y, px1.z, px1.w};
            float pr1[8] = {py0.x, py0.y, py0.z, py0.w, py1.x, py1.y, py1.z, py1.w};
            float pr2[8] = {pz0.x, pz0.y, pz0.z, pz0.w, pz1.x, pz1.y, pz1.z, pz1.w};
            const float* la  = &tL[tr + (wave == 2 ? 0 : 1)][j0];
            const float* lb2 = &tL[tr + (wave == 2 ? 1 : 2)][j0];
            float4 la0 = *(const float4*)(la);
            float4 la1 = *(const float4*)(la + 4);
            float4 lb0 = *(const float4*)(lb2);
            float4 lb1 = *(const float4*)(lb2 + 4);
            float lrA[8] = {la0.x, la0.y, la0.z, la0.w, la1.x, la1.y, la1.z, la1.w};
            float lrB[8] = {lb0.x, lb0.y, lb0.z, lb0.w, lb1.x, lb1.y, lb1.z, lb1.w};
            #pragma unroll
            for (int q = 0; q < 4; ++q) {
                float sel = (j0 + q < NWW) ? 1.f : 0.f;
                float vp[9];
                vp[0] = pr0[q]; vp[1] = pr0[q + 1]; vp[2] = pr0[q + 2];
                vp[3] = pr1[q]; vp[4] = pr1[q + 1]; vp[5] = pr1[q + 2];
                vp[6] = pr2[q]; vp[7] = pr2[q + 1]; vp[8] = pr2[q + 2];
                float vl[5];
                if (wave == 2) {
                    vl[0] = lrA[q] * sel; vl[1] = lrA[q + 1] * sel; vl[2] = lrA[q + 2] * sel;
                    vl[3] = lrB[q] * sel; vl[4] = lrB[q + 1] * sel;
                } else {
                    vl[0] = lrA[q + 2] * sel;
                    vl[1] = lrB[q] * sel; vl[2] = lrB[q + 1] * sel; vl[3] = lrB[q + 2] * sel;
                }
                #pragma unroll
                for (int d = 0; d < 5; ++d) {
                    if (d < nd) {
                        #pragma unroll
                        for (int e = 0; e < 9; ++e)
                            acc[d * 9 + e] += vl[d] * vp[e];
                    }
                }
            }
        }
        const int nred = nd * 9;
        #pragma unroll
        for (int k = 0; k < 45; ++k) {
            if (k < nred) {
                float x = acc[k];
                #pragma unroll
                for (int off = 32; off > 0; off >>= 1) x += __shfl_down(x, off);
                if (lane == 0) pbase[(size_t)(90 + dof * 9 + k) * NCT] = x;
            }
        }
    }
}

// ---------- Kernel 2: cooperative per-(n,c) 9x9 algebra ----------
__global__ __launch_bounds__(128) void solve_kernel(const float* __restrict__ partial,
                                                    double* __restrict__ per_nc) {
    const int nc = blockIdx.x;
    const int tid = threadIdx.x;
    __shared__ double cl[45], cp[45], clp[81], sL[9], sP[9];
    __shared__ double All[81], C[81], Pm[81], X[81], A[81];
    __shared__ double logacc;

    for (int s = tid; s < NSLOT; s += 128) {
        double acc = 0.0;
        for (int ch = 0; ch < NCHUNK; ++ch)
            acc += (double)partial[((size_t)ch * NSLOT + s) * NCT + nc];
        if (s < 45)       cl[s] = acc;
        else if (s < 90)  cp[s - 45] = acc;
        else if (s < 171) clp[s - 90] = acc;
        else if (s < 180) sL[s - 171] = acc;
        else              sP[s - 180] = acc;
    }
    if (tid == 0) logacc = 0.0;
    __syncthreads();

    const double M = (double)MPTS;
    if (tid < 81) {
        int d = tid / 9, e = tid % 9;
        int lo = d < e ? d : e, hi = d < e ? e : d;
        int k = 9 * lo - lo * (lo - 1) / 2 + (hi - lo);
        All[tid] = cl[k] - sL[d] * sL[e] / M;
        C[tid]   = cp[k] - sP[d] * sP[e] / M + (d == e ? 1e-3 : 0.0);
        Pm[tid]  = clp[tid] - sL[d] * sP[e] / M;
    }
    __syncthreads();

    for (int k = 0; k < 9; ++k) {
        if (tid == 0) C[k * 9 + k] = sqrt(fmax(C[k * 9 + k], 1e-30));
        __syncthreads();
        if (tid > k && tid < 9) C[tid * 9 + k] /= C[k * 9 + k];
        __syncthreads();
        if (tid < 81) {
            int i = tid / 9, j = tid % 9;
            if (j > k && i >= j) C[i * 9 + j] -= C[i * 9 + k] * C[j * 9 + k];
        }
        __syncthreads();
    }

    for (int e = 0; e < 9; ++e) {
        if (tid < 9) {
            int d = tid;
            double sum = Pm[d * 9 + e];
            for (int k = 0; k < e; ++k) sum -= C[e * 9 + k] * X[k * 9 + d];
            X[e * 9 + d] = sum / C[e * 9 + e];
        }
        __syncthreads();
    }

    if (tid < 81) {
        int d = tid / 9, g = tid % 9;
        double w = 0.0;
        #pragma unroll
        for (int e = 0; e < 9; ++e) w += X[e * 9 + d] * X[e * 9 + g];
        A[tid] = All[tid] - w + (d == g ? 1e-3 : 0.0);
    }
    __syncthreads();

    for (int k = 0; k < 9; ++k) {
        if (tid == 0) {
            double piv = sqrt(fmax(A[k * 9 + k], 0.0));
            A[k * 9 + k] = piv;
            logacc += log(piv + 1e-8);
        }
        __syncthreads();
        if (tid > k && tid < 9) A[tid * 9 + k] /= A[k * 9 + k];
        __syncthreads();
        if (tid < 81) {
            int i = tid / 9, j = tid % 9;
            if (j > k && i >= j) A[i * 9 + j] -= A[i * 9 + k] * A[j * 9 + k];
        }
        __syncthreads();
    }
    if (tid == 0) per_nc[nc] = logacc;
}

// ---------- Kernel 3: final reduction ----------
__global__ __launch_bounds__(128) void reduce_kernel(const double* __restrict__ per_nc,
                                                     float* __restrict__ out) {
    int t = threadIdx.x;
    double r = (t < NCT) ? per_nc[t] : 0.0;
    __shared__ double red[128];
    red[t] = r;
    __syncthreads();
    for (int s = 64; s > 0; s >>= 1) {
        if (t < s) red[t] += red[t + s];
        __syncthreads();
    }
    if (t == 0) out[0] = (float)(red[0] / 36.0);
}

extern "C" void kernel_launch(void* const* d_in, const int* in_sizes, int n_in,
                              void* d_out, int out_size, void* d_ws, size_t ws_size,
                              hipStream_t stream) {
    const float* cls  = (const float*)d_in[0];
    const float* tgt  = (const float*)d_in[1];
    const float* mask = (const float*)d_in[2];

    double* per_nc  = (double*)d_ws;                     // 128 doubles
    float*  partial = (float*)(per_nc + 128);            // NCHUNK*NSLOT*NCT floats

    dim3 gfused(NCT, NCHUNK);
    fused_kernel<<<gfused, 256, 0, stream>>>(cls, tgt, mask, partial);

    solve_kernel<<<NCT, 128, 0, stream>>>(partial, per_nc);

    reduce_kernel<<<1, 128, 0, stream>>>(per_nc, (float*)d_out);
}